// Round 4
// baseline (638.677 us; speedup 1.0000x reference)
//
#include <hip/hip_runtime.h>
#include <hip/hip_bf16.h>
#include <stdint.h>

// Problem constants
#define DIN   4096
#define DOUT  4096
#define RANK  16
#define NSUB  4
#define MTOT  8192            // B*S = 4*2048
#define LDK   4160            // 4096 + 64 sub-adapter cols; 4160 = 65*64
#define KTAIL 64              // NSUB*RANK
#define NV    80              // 64 sub_A rows + 4 gate rows + 12 zero pad

typedef __attribute__((ext_vector_type(8)))  short    short8;   // 8 bf16 (4 VGPRs)
typedef __attribute__((ext_vector_type(4)))  float    floatx4;
typedef __attribute__((ext_vector_type(8)))  unsigned short ushort8;
typedef __attribute__((ext_vector_type(4)))  unsigned short ushort4v;

static __device__ __forceinline__ unsigned short f2bf(float f) {
    unsigned int u = __float_as_uint(f);
    unsigned int r = (u + 0x7FFFu + ((u >> 16) & 1u)) >> 16;   // RNE
    return (unsigned short)r;
}

static __device__ __forceinline__ void async_copy16(const unsigned short* g, unsigned short* l) {
    __builtin_amdgcn_global_load_lds(
        (const __attribute__((address_space(1))) unsigned int*)g,
        (__attribute__((address_space(3))) unsigned int*)l,
        16, 0, 0);
}

// ---------------------------------------------------------------------------
// Kernel 0: build Vc in CHUNK-MAJOR layout: Vc[chunk][NV][256] bf16, where
// chunk = col/256. Rows 0..63 = sub_A (flat), 64..67 = sub_wgate, 68..79 = 0.
// Chunk-major makes each 40KB slab contiguous for async global_load_lds.
// ---------------------------------------------------------------------------
__global__ __launch_bounds__(256) void build_v_kernel(
    const float* __restrict__ sub_wgate,
    const float* __restrict__ sub_A,
    unsigned short* __restrict__ Vc)
{
    const int t = threadIdx.x;
    const int row = blockIdx.x;      // 0..79
    const float* src = (row < 64) ? (sub_A + (size_t)row * DIN)
                     : (row < 68) ? (sub_wgate + (size_t)(row - 64) * DIN)
                     : nullptr;
#pragma unroll
    for (int i = 0; i < 4; ++i) {
        int c4 = t + 256 * i;          // float4 index, 0..1023
        ushort4v v;
        if (src) {
            float4 a = ((const float4*)src)[c4];
            v[0] = f2bf(a.x); v[1] = f2bf(a.y); v[2] = f2bf(a.z); v[3] = f2bf(a.w);
        } else {
            v[0] = v[1] = v[2] = v[3] = 0;
        }
        int chunk = c4 >> 6;                   // col/256
        int cin   = (c4 * 4) & 255;
        *(ushort4v*)(Vc + ((size_t)chunk * NV + row) * 256 + cin) = v;
    }
}

// ---------------------------------------------------------------------------
// Kernel 1 (v3): fused build of X_cat [MTOT][LDK] bf16.
//   cols 0..4095: bf16(x)   (single HBM pass over x)
//   cols 4096+c:  2 * relu(P[tok][64+(c>>4)]) * P[tok][c],  P = x_bf16 @ Vc^T
// 16 tokens/block, grid 512, 4 waves k-split each 256-col chunk (2 ks each).
// Vc chunk (40KB) staged via async global_load_lds into UNPADDED Bs[80][256]
// with XOR swizzle (chunk^=row&7) applied on the global-address side so the
// b128 fragment reads hit the 8-phase bank floor. x staged synchronously
// (needs fp32->bf16 cvt) into As with LDA=272 pad (16B-aligned, floor banks).
// ---------------------------------------------------------------------------
#define LDA 272
__global__ __launch_bounds__(256) void build_x_kernel(
    const float* __restrict__ x,
    const unsigned short* __restrict__ Vc,
    unsigned short* __restrict__ Xc)
{
    __shared__ char smem[16 * LDA * 2 + NV * 256 * 2];   // 8704 + 40960 = 49664 B
    unsigned short* As = (unsigned short*)smem;          // [16][LDA] padded
    unsigned short* Bs = As + 16 * LDA;                  // [NV][256] unpadded
    float* Pp = (float*)smem;                            // [4][16][NV], reused

    const int t  = threadIdx.x;
    const int l  = t & 63;
    const int w  = t >> 6;        // wave = k-quarter
    const int m0 = blockIdx.x * 16;
    const int lane16 = l & 15;
    const int q      = l >> 4;    // 0..3
    const int kq     = q * 8;

    floatx4 acc[5] = {};

    for (int cc = 0; cc < DIN; cc += 256) {
        // async stage Vc chunk slab (40KB contiguous), swizzled gather
        const unsigned short* slab = Vc + (size_t)(cc >> 8) * (NV * 256);
#pragma unroll
        for (int j = 0; j < 10; ++j) {
            int sb  = w * 10 + j;                  // 1KB sub-slab 0..39
            int row = sb * 2 + (l >> 5);
            const unsigned short* g = slab + row * 256 + (((l & 31) ^ (row & 7)) * 8);
            async_copy16(g, Bs + sb * 512 + l * 8);
        }
        // sync stage x chunk [16][256]: fp32 -> bf16 -> LDS + global Xc
#pragma unroll
        for (int i = 0; i < 2; ++i) {
            int u8 = t + 256 * i;        // 0..511
            int tr = u8 >> 5;            // 32 ushort8 per row
            int c8 = u8 & 31;
            const float4* src = (const float4*)(x + (size_t)(m0 + tr) * DIN + cc + c8 * 8);
            float4 a = src[0], b = src[1];
            ushort8 v;
            v[0] = f2bf(a.x); v[1] = f2bf(a.y); v[2] = f2bf(a.z); v[3] = f2bf(a.w);
            v[4] = f2bf(b.x); v[5] = f2bf(b.y); v[6] = f2bf(b.z); v[7] = f2bf(b.w);
            *(ushort8*)&As[tr * LDA + c8 * 8] = v;
            *(ushort8*)(Xc + (size_t)(m0 + tr) * LDK + cc + c8 * 8) = v;
        }
        __syncthreads();

        // MFMA: wave w handles k-steps {2w, 2w+1} of the 8 in this chunk
#pragma unroll
        for (int s = 0; s < 2; ++s) {
            int ks = w * 2 + s;
            short8 af = *(const short8*)&As[lane16 * LDA + ks * 32 + kq];
            int C = ks * 4 + q;                    // 16B chunk index 0..31
#pragma unroll
            for (int n = 0; n < 5; ++n) {
                short8 bf = *(const short8*)&Bs[(n * 16 + lane16) * 256 + ((C ^ (lane16 & 7)) * 8)];
                acc[n] = __builtin_amdgcn_mfma_f32_16x16x32_bf16(af, bf, acc[n], 0, 0, 0);
            }
        }
        __syncthreads();
    }

    // dump partial P (C/D layout: col=lane&15, row=(l>>4)*4+reg)
#pragma unroll
    for (int n = 0; n < 5; ++n)
#pragma unroll
        for (int r = 0; r < 4; ++r)
            Pp[(w * 16 + q * 4 + r) * NV + n * 16 + lane16] = acc[n][r];
    __syncthreads();

    // gated tail: 16 tokens x 64 cols, summing the 4 k-partials
#pragma unroll
    for (int i = 0; i < 4; ++i) {
        int v  = t + 256 * i;            // 0..1023
        int tr = v >> 6;
        int c  = v & 63;
        int j  = c >> 4;
        float ps = 0.f, gs = 0.f;
#pragma unroll
        for (int qq = 0; qq < 4; ++qq) {
            ps += Pp[(qq * 16 + tr) * NV + c];
            gs += Pp[(qq * 16 + tr) * NV + 64 + j];
        }
        Xc[(size_t)(m0 + tr) * LDK + DIN + c] = f2bf(2.0f * fmaxf(gs, 0.f) * ps);
    }
}

// ---------------------------------------------------------------------------
// Kernel 2: build W_cat [DOUT][LDK] bf16 — streaming (unchanged from R3).
// ---------------------------------------------------------------------------
__global__ __launch_bounds__(256) void build_w_kernel(
    const float* __restrict__ W,        // [DOUT][DIN]
    const float* __restrict__ base_A,   // [RANK][DIN]
    const float* __restrict__ base_B,   // [DOUT][RANK]
    const float* __restrict__ sub_B,    // [NSUB][DOUT][RANK]
    unsigned short* __restrict__ Wc)
{
    __shared__ float bBs[8 * RANK];

    const int t  = threadIdx.x;
    const int o0 = (blockIdx.x >> 2) * 8;
    const int cc = (blockIdx.x & 3) * 1024;
    const int q  = (cc >> 2) + t;        // float4 index into a DIN row

    if (t < 128) bBs[t] = 2.0f * base_B[(size_t)o0 * RANK + t];
    __syncthreads();

    float4 acc[8];
#pragma unroll
    for (int o = 0; o < 8; ++o)
        acc[o] = ((const float4*)(W + (size_t)(o0 + o) * DIN))[q];

#pragma unroll
    for (int r = 0; r < RANK; ++r) {
        float4 a = ((const float4*)(base_A + (size_t)r * DIN))[q];
#pragma unroll
        for (int o = 0; o < 8; ++o) {
            float s = bBs[o * RANK + r];
            acc[o].x += s * a.x; acc[o].y += s * a.y;
            acc[o].z += s * a.z; acc[o].w += s * a.w;
        }
    }

#pragma unroll
    for (int o = 0; o < 8; ++o) {
        ushort4v v;
        v[0] = f2bf(acc[o].x); v[1] = f2bf(acc[o].y);
        v[2] = f2bf(acc[o].z); v[3] = f2bf(acc[o].w);
        *(ushort4v*)(Wc + (size_t)(o0 + o) * LDK + q * 4) = v;
    }

    if ((blockIdx.x & 3) == 0) {
#pragma unroll
        for (int i = 0; i < 2; ++i) {
            int v = t + 256 * i;             // 0..511
            int o = v >> 6;
            int c = v & 63;
            int j = c >> 4;
            int r = c & 15;
            float s = sub_B[((size_t)j * DOUT + (o0 + o)) * RANK + r];
            Wc[(size_t)(o0 + o) * LDK + DIN + c] = f2bf(s);
        }
    }
}

// ---------------------------------------------------------------------------
// Kernel 3 (v2): out = X_cat @ W_cat^T + bias. 128x128 tile, 4 waves (2x2),
// BK=64 (32KB LDS -> 4 blocks/CU; halves barrier-drain count vs BK=32).
// Staging via async global_load_lds (8x16B per thread/iter) with XOR swizzle
// (k-chunk ^= row&7) on the global side: LDS dest stays lane-contiguous
// (async requirement) while b128 fragment reads hit the 8-phase bank floor.
// K = 4160 = 65 iterations.
// ---------------------------------------------------------------------------
__global__ __launch_bounds__(256) void gemm_kernel(
    const unsigned short* __restrict__ Xc,
    const unsigned short* __restrict__ Wc,
    const float* __restrict__ bias,
    float* __restrict__ out)
{
    __shared__ unsigned short smem[16384];   // As[128][64] + Bs[128][64]
    unsigned short* As = smem;
    unsigned short* Bs = smem + 8192;

    const int t  = threadIdx.x;
    const int l  = t & 63;
    const int wm = (t >> 6) >> 1;
    const int wn = (t >> 6) & 1;
    const int m0 = blockIdx.y * 128;
    const int n0 = blockIdx.x * 128;

    floatx4 acc[4][4] = {};

    // staging decode: instr i in 0..3, LDS bytes = i*4096 + t*16
    //   row = i*32 + (t>>3); slot = t&7; fetched chunk = slot ^ (row&7)
    const int row_i = t >> 3;            // 0..31
    const int slot  = t & 7;
    const int fch   = slot ^ (row_i & 7);   // row&7 == row_i&7 (i*32 = 0 mod 8)
    const unsigned short* gA[4];
    const unsigned short* gB[4];
    unsigned short *lA[4], *lB[4];
#pragma unroll
    for (int i = 0; i < 4; ++i) {
        int row = i * 32 + row_i;
        gA[i] = Xc + (size_t)(m0 + row) * LDK + fch * 8;
        gB[i] = Wc + (size_t)(n0 + row) * LDK + fch * 8;
        lA[i] = As + i * 2048 + t * 8;
        lB[i] = Bs + i * 2048 + t * 8;
    }

    const int q      = l >> 4;           // 0..3
    const int lane16 = l & 15;
    const int sw     = lane16 & 7;       // read-side swizzle key

    for (int kk = 0; kk < LDK; kk += 64) {
#pragma unroll
        for (int i = 0; i < 4; ++i) {
            async_copy16(gA[i] + kk, lA[i]);
            async_copy16(gB[i] + kk, lB[i]);
        }
        __syncthreads();

#pragma unroll
        for (int ks2 = 0; ks2 < 2; ++ks2) {
            int C = ks2 * 4 + q;         // 16B k-chunk 0..7
            int Cs = (C ^ sw) * 8;       // swizzled short offset
            short8 af[4], bf[4];
#pragma unroll
            for (int i = 0; i < 4; ++i) {
                af[i] = *(const short8*)&As[(wm * 64 + i * 16 + lane16) * 64 + Cs];
                bf[i] = *(const short8*)&Bs[(wn * 64 + i * 16 + lane16) * 64 + Cs];
            }
#pragma unroll
            for (int i = 0; i < 4; ++i)
#pragma unroll
                for (int j = 0; j < 4; ++j)
                    acc[i][j] = __builtin_amdgcn_mfma_f32_16x16x32_bf16(af[i], bf[j], acc[i][j], 0, 0, 0);
        }
        __syncthreads();
    }

    // epilogue: C/D layout col = lane&15, row = (lane>>4)*4 + reg
    const int row_l = q * 4;
#pragma unroll
    for (int j = 0; j < 4; ++j) {
        int gcol = n0 + wn * 64 + j * 16 + lane16;
        float bv = bias[gcol];
#pragma unroll
        for (int i = 0; i < 4; ++i) {
            int grow = m0 + wm * 64 + i * 16 + row_l;
            size_t base = (size_t)grow * DOUT + gcol;
            out[base]            = acc[i][j][0] + bv;
            out[base + DOUT]     = acc[i][j][1] + bv;
            out[base + 2 * DOUT] = acc[i][j][2] + bv;
            out[base + 3 * DOUT] = acc[i][j][3] + bv;
        }
    }
}

// ---------------------------------------------------------------------------
extern "C" void kernel_launch(void* const* d_in, const int* in_sizes, int n_in,
                              void* d_out, int out_size, void* d_ws, size_t ws_size,
                              hipStream_t stream) {
    const float* x         = (const float*)d_in[0];
    const float* base_W    = (const float*)d_in[1];
    const float* base_b    = (const float*)d_in[2];
    const float* base_A    = (const float*)d_in[3];
    const float* base_B    = (const float*)d_in[4];
    const float* sub_wgate = (const float*)d_in[5];
    const float* sub_A     = (const float*)d_in[6];
    const float* sub_B     = (const float*)d_in[7];
    float* out = (float*)d_out;

    // workspace: X_cat [8192][4160], W_cat [4096][4160], Vc_chunked [16][80][256]
    unsigned short* Xc = (unsigned short*)d_ws;
    unsigned short* Wc = Xc + (size_t)MTOT * LDK;
    unsigned short* Vc = Wc + (size_t)DOUT * LDK;

    build_v_kernel<<<NV, 256, 0, stream>>>(sub_wgate, sub_A, Vc);
    build_x_kernel<<<MTOT / 16, 256, 0, stream>>>(x, Vc, Xc);
    build_w_kernel<<<(DOUT / 8) * 4, 256, 0, stream>>>(base_W, base_A, base_B, sub_B, Wc);
    gemm_kernel<<<dim3(DOUT / 128, MTOT / 128), 256, 0, stream>>>(Xc, Wc, base_b, out);
}